// Round 5
// baseline (348.421 us; speedup 1.0000x reference)
//
#include <hip/hip_runtime.h>

#define Bdim 16
#define Cdim 32
#define Ndim 207
#define X_B (Cdim * Ndim * 64)      // 423936
#define X_C (Ndim * 64)             // 13248
#define W_C (Ndim * 64 * 64 * 2)    // 1695744
#define W_N (64 * 64 * 2)           // 8192
#define BN_EVAL 0.9999950000374997f

using s8v = __attribute__((ext_vector_type(8))) short;
using f4v = __attribute__((ext_vector_type(4))) float;

union UV { uint4 u; s8v s; };

// pack {bf16(lo), bf16(hi)} by truncation: 1 v_perm_b32
__device__ __forceinline__ unsigned pk(float lo, float hi) {
    union { float f; unsigned u; } a, b;
    a.f = lo; b.f = hi;
    return __builtin_amdgcn_perm(b.u, a.u, 0x07060302u);
}

__global__ __launch_bounds__(256, 6)
void fused_ml_mfma(const float* __restrict__ x,
                   const float* __restrict__ rw,
                   const float* __restrict__ rb,
                   const float* __restrict__ mw,
                   const float* __restrict__ mb,
                   const float* __restrict__ gw,
                   const float* __restrict__ gb,
                   const float* __restrict__ ow,
                   const float* __restrict__ obp,
                   float* __restrict__ out)
{
    const int cn = blockIdx.x, c = cn / Ndim, n = cn % Ndim;
    const int t = threadIdx.x;
    const int l = t & 63, w = t >> 6, q = l >> 4, nn = l & 15;
    const int o = w * 16 + nn;                 // this wave's o column (B-frag col = lane&15)

    const float ow0 = ow[0], ow1 = ow[1];
    const float bnow1 = ow1 * BN_EVAL;

    // lane nn's x row (A-frag row = lane&15 = b index)
    const float* xrow  = x + (size_t)nn * X_B + (size_t)c * X_C + n * 64;
    const float* wtile = rw + (size_t)c * W_C + (size_t)n * W_N + o * 2;

    f4v accU = {0.f, 0.f, 0.f, 0.f};
    f4v accM = {0.f, 0.f, 0.f, 0.f};
    f4v accG = {0.f, 0.f, 0.f, 0.f};

    // ---- grouped matmul: K=128, kappa=2i+d; A and B both built in-register ----
#pragma unroll
    for (int s = 0; s < 4; ++s) {
        const int i0 = 16 * s + 4 * q;
        const float4 xv = *(const float4*)(xrow + i0);       // x[nn][i0..i0+3]
        UV au;
        au.u.x = pk(xv.x * ow0, xv.x * xv.x * bnow1);
        au.u.y = pk(xv.y * ow0, xv.y * xv.y * bnow1);
        au.u.z = pk(xv.z * ow0, xv.z * xv.z * bnow1);
        au.u.w = pk(xv.w * ow0, xv.w * xv.w * bnow1);

        const float* gp = wtile + (size_t)i0 * 128;
        const float2 w0 = *(const float2*)(gp);
        const float2 w1 = *(const float2*)(gp + 128);
        const float2 w2 = *(const float2*)(gp + 256);
        const float2 w3 = *(const float2*)(gp + 384);
        UV bu;
        bu.u.x = pk(w0.x, w0.y); bu.u.y = pk(w1.x, w1.y);
        bu.u.z = pk(w2.x, w2.y); bu.u.w = pk(w3.x, w3.y);

        accU = __builtin_amdgcn_mfma_f32_16x16x32_bf16(au.s, bu.s, accU, 0, 0, 0);
    }

    // ---- shared mlp+gate matmuls: K=64, all frags in-register ----
#pragma unroll
    for (int s = 0; s < 2; ++s) {
        const int i0 = 32 * s + 8 * q;
        const float4 xa = *(const float4*)(xrow + i0);
        const float4 xb = *(const float4*)(xrow + i0 + 4);
        UV a2;
        a2.u.x = pk(xa.x, xa.y); a2.u.y = pk(xa.z, xa.w);
        a2.u.z = pk(xb.x, xb.y); a2.u.w = pk(xb.z, xb.w);

        const float4 m0 = *(const float4*)(mw + o * 64 + i0);
        const float4 m1 = *(const float4*)(mw + o * 64 + i0 + 4);
        UV bm;
        bm.u.x = pk(m0.x, m0.y); bm.u.y = pk(m0.z, m0.w);
        bm.u.z = pk(m1.x, m1.y); bm.u.w = pk(m1.z, m1.w);

        const float4 g0 = *(const float4*)(gw + o * 64 + i0);
        const float4 g1 = *(const float4*)(gw + o * 64 + i0 + 4);
        UV bg2;
        bg2.u.x = pk(g0.x, g0.y); bg2.u.y = pk(g0.z, g0.w);
        bg2.u.z = pk(g1.x, g1.y); bg2.u.w = pk(g1.z, g1.w);

        accM = __builtin_amdgcn_mfma_f32_16x16x32_bf16(a2.s, bm.s,  accM, 0, 0, 0);
        accG = __builtin_amdgcn_mfma_f32_16x16x32_bf16(a2.s, bg2.s, accG, 0, 0, 0);
    }

    // ---- epilogue: D row = q*4 + reg, col = o ----
    const float rbias = rb[c * Ndim + n];
    const float uconst = rbias * (ow0 + ow1) + obp[0];
    const float mbias = mb[o], gbias = gb[o];
    const float* xcol = x + (size_t)c * X_C + n * 64 + o;
    float* ocol = out + (size_t)c * X_C + n * 64 + o;
#pragma unroll
    for (int r = 0; r < 4; ++r) {
        const int b = q * 4 + r;
        const float uniq = (accU[r] + uconst) * 0.125f;   // SCALE/4
        const float xs = accM[r] + mbias;
        const float g = 1.f / (1.f + __expf(-(accG[r] + gbias)));
        const float xres = xcol[(size_t)b * X_B];
        ocol[(size_t)b * X_B] = g * uniq + (1.f - g) * xs + xres;
    }
}

extern "C" void kernel_launch(void* const* d_in, const int* in_sizes, int n_in,
                              void* d_out, int out_size, void* d_ws, size_t ws_size,
                              hipStream_t stream)
{
    const float* x   = (const float*)d_in[0];
    const float* rw  = (const float*)d_in[1];
    const float* rb  = (const float*)d_in[2];
    const float* mw  = (const float*)d_in[3];
    const float* mb  = (const float*)d_in[4];
    const float* gw  = (const float*)d_in[5];
    const float* gb  = (const float*)d_in[6];
    const float* ow  = (const float*)d_in[7];
    const float* ob  = (const float*)d_in[8];
    float* out = (float*)d_out;

    fused_ml_mfma<<<dim3(Cdim * Ndim), dim3(256), 0, stream>>>(
        x, rw, rb, mw, mb, gw, gb, ow, ob, out);
}